// Round 14
// baseline (158.734 us; speedup 1.0000x reference)
//
#include <hip/hip_runtime.h>
#include <stdint.h>

#define BATCH 16
#define NPTS 4096
#define DIM 384
#define NTOK (2*NPTS)
#define F4PT (DIM/4)   // 96 float4 groups per token

typedef unsigned long long u64;

// Morton spread: place bit b of an 8-bit value at position 3b.
__device__ __forceinline__ uint32_t spread3(uint32_t x) {
    x = (x | (x << 8)) & 0x00F00Fu;
    x = (x | (x << 4)) & 0x0C30C3u;
    x = (x | (x << 2)) & 0x249249u;
    return x;
}

// Exact port of the reference Skilling transform (bits=8, ndim=3).
__device__ __forceinline__ uint32_t hilbert3(uint32_t x0, uint32_t x1, uint32_t x2) {
    #pragma unroll
    for (uint32_t q = 128; q > 1; q >>= 1) {
        uint32_t pm = q - 1;
        if (x0 & q) x0 ^= pm;
        uint32_t t = (x0 ^ x1) & pm;
        if (x1 & q) { x0 ^= pm; } else { x0 ^= t; x1 ^= t; }
        t = (x0 ^ x2) & pm;
        if (x2 & q) { x0 ^= pm; } else { x0 ^= t; x2 ^= t; }
    }
    x1 ^= x0;
    x2 ^= x1;
    uint32_t t = 0;
    #pragma unroll
    for (uint32_t q = 128; q > 1; q >>= 1) { if (x2 & q) t ^= (q - 1); }
    x0 ^= t; x1 ^= t; x2 ^= t;
    return (spread3(x0) << 2) | (spread3(x1) << 1) | spread3(x2);
}

struct S1 {   // radix phase
    u64 skey[512];               // 4 KB
    uint32_t hist[3 * 2048];     // 24 KB
    uint32_t baseArr[256];       // 1 KB
    uint32_t waveTot[4];
    float red[8 * 6];
};
struct S2 {   // merge/emit phase
    u64 runs[8 * 512];                   // 32 KB
    float cxs[512], cys[512], czs[512];  // 6 KB
    int rnk[512];                        // 2 KB
};
union ShU { S1 a; S2 b; };

// Single launch, 256 blocks (1/CU, co-resident) x 512 threads.
// Block bi=(b<<4)|(v<<3)|oct. Phase 1: minmax+code+3-pass radix -> kws run.
// Release: threadfence + atomicAdd(done[g]). Spin until done[g]==8 (8
// producers per flag). Acquire: threadfence. Phase 2: merge + direct emit.
__global__ __launch_bounds__(512) void fused_kernel(const float* __restrict__ x,
                                                    const float* __restrict__ W,
                                                    const float* __restrict__ bias,
                                                    const float* __restrict__ gamma,
                                                    const float* __restrict__ beta,
                                                    u64* __restrict__ kws,
                                                    int* __restrict__ done,
                                                    float4* __restrict__ out4) {
    const int bi = blockIdx.x;
    const int b = bi >> 4;
    const int v = (bi >> 3) & 1;
    const int oct = bi & 7;
    const int t = threadIdx.x;
    const int lane = t & 63;
    const int w = t >> 6;          // 8 waves

    __shared__ ShU sh;                                                   // 41 KB
    __shared__ __align__(16) float sw0[DIM], sw1[DIM], sw2[DIM], sc[DIM]; // 6 KB

    const float* xb = x + (size_t)b * NPTS * 3;
    const float4* xb4 = (const float4*)xb;

    // Coeff staging (independent; overlaps minmax).
    if (t < DIM) {
        float g = gamma[v * DIM + t];
        sw0[t] = g * W[t*3+0];
        sw1[t] = g * W[t*3+1];
        sw2[t] = g * W[t*3+2];
        sc[t]  = g * bias[t] + beta[v * DIM + t];
    }

    // --- vectorized batch min/max: 8 points/thread (48 KB, L2-hot) ---
    float mnx = 1e30f, mny = 1e30f, mnz = 1e30f;
    float mxx = -1e30f, mxy = -1e30f, mxz = -1e30f;
    #pragma unroll
    for (int h = 0; h < 2; ++h) {
        float4 q0 = xb4[h * 1536 + 3 * t + 0];
        float4 q1 = xb4[h * 1536 + 3 * t + 1];
        float4 q2 = xb4[h * 1536 + 3 * t + 2];
        float px[4] = {q0.x, q0.w, q1.z, q2.y};
        float py[4] = {q0.y, q1.x, q1.w, q2.z};
        float pz[4] = {q0.z, q1.y, q2.x, q2.w};
        #pragma unroll
        for (int r = 0; r < 4; ++r) {
            mnx = fminf(mnx, px[r]); mxx = fmaxf(mxx, px[r]);
            mny = fminf(mny, py[r]); mxy = fmaxf(mxy, py[r]);
            mnz = fminf(mnz, pz[r]); mxz = fmaxf(mxz, pz[r]);
        }
    }
    #pragma unroll
    for (int off = 32; off > 0; off >>= 1) {
        mnx = fminf(mnx, __shfl_xor(mnx, off));
        mny = fminf(mny, __shfl_xor(mny, off));
        mnz = fminf(mnz, __shfl_xor(mnz, off));
        mxx = fmaxf(mxx, __shfl_xor(mxx, off));
        mxy = fmaxf(mxy, __shfl_xor(mxy, off));
        mxz = fmaxf(mxz, __shfl_xor(mxz, off));
    }
    if (lane == 0) {
        sh.a.red[w*6+0] = mnx; sh.a.red[w*6+1] = mny; sh.a.red[w*6+2] = mnz;
        sh.a.red[w*6+3] = mxx; sh.a.red[w*6+4] = mxy; sh.a.red[w*6+5] = mxz;
    }
    // Zero all per-pass hist regions while the reduction settles.
    #pragma unroll
    for (int c = 0; c < 12; ++c) sh.a.hist[t + c * 512] = 0u;
    __syncthreads();
    if (t == 0) {
        for (int ww = 1; ww < 8; ++ww) {
            mnx = fminf(mnx, sh.a.red[ww*6+0]); mny = fminf(mny, sh.a.red[ww*6+1]);
            mnz = fminf(mnz, sh.a.red[ww*6+2]); mxx = fmaxf(mxx, sh.a.red[ww*6+3]);
            mxy = fmaxf(mxy, sh.a.red[ww*6+4]); mxz = fmaxf(mxz, sh.a.red[ww*6+5]);
        }
        sh.a.red[0] = mnx; sh.a.red[1] = mny; sh.a.red[2] = mnz;
        sh.a.red[3] = fmaxf(mxx - mnx, 1e-6f);
        sh.a.red[4] = fmaxf(mxy - mny, 1e-6f);
        sh.a.red[5] = fmaxf(mxz - mnz, 1e-6f);
    }
    __syncthreads();
    mnx = sh.a.red[0]; mny = sh.a.red[1]; mnz = sh.a.red[2];
    const float spx = sh.a.red[3], spy = sh.a.red[4], spz = sh.a.red[5];

    // Code own point n0 = oct*512 + t.
    u64 key;
    {
        const int n0 = (oct << 9) + t;
        float cx = xb[3*n0+0], cy = xb[3*n0+1], cz = xb[3*n0+2];
        float gx = fminf(fmaxf(((cx - mnx) / spx) * 255.0f, 0.0f), 255.0f);
        float gy = fminf(fmaxf(((cy - mny) / spy) * 255.0f, 0.0f), 255.0f);
        float gz = fminf(fmaxf(((cz - mnz) / spz) * 255.0f, 0.0f), 255.0f);
        uint32_t ix = (uint32_t)(int)gx;
        uint32_t iy = (uint32_t)(int)gy;
        uint32_t iz = (uint32_t)(int)gz;
        uint32_t a0 = v ? iz : ix;
        uint32_t a2 = v ? ix : iz;
        uint32_t code = hilbert3(a0, iy, a2);
        key = ((u64)code << 12) | (u64)n0;
    }

    const u64 below_mask = (1ull << lane) - 1ull;
    u64* segk = kws + (((b << 1) | v) << 12);
    const int g = (b << 1) | v;

    // 3 stable radix passes, 8-bit digits over key bits [12, 36).
    #pragma unroll
    for (int p = 0; p < 3; ++p) {
        const int sh4 = 12 + 8 * p;
        uint32_t* histp = sh.a.hist + p * 2048;

        unsigned d = (unsigned)(key >> sh4) & 255u;
        u64 m = ~0ull;
        #pragma unroll
        for (int bit = 0; bit < 8; ++bit) {
            u64 bal = __ballot((int)((d >> bit) & 1u));
            m &= ((d >> bit) & 1u) ? bal : ~bal;
        }
        unsigned rk = (unsigned)__popcll(m & below_mask);
        if (rk == 0u)
            histp[d * 8 + w] = (unsigned)__popcll(m);
        __syncthreads();   // B1

        unsigned exclw = 0;
        if (t < 256) {
            uint32_t* hb = histp + t * 8;
            unsigned running = 0;
            #pragma unroll
            for (int s = 0; s < 8; ++s) {
                unsigned hv = hb[s];
                hb[s] = running;
                running += hv;
            }
            unsigned incl = running;
            #pragma unroll
            for (int off = 1; off < 64; off <<= 1) {
                unsigned nv = __shfl_up(incl, off);
                if (lane >= off) incl += nv;
            }
            if (lane == 63) sh.a.waveTot[w] = incl;
            exclw = incl - running;
        }
        __syncthreads();   // B1.5

        if (t < 256) {
            unsigned base = exclw;
            #pragma unroll
            for (int ww = 0; ww < 4; ++ww)
                if (ww < w) base += sh.a.waveTot[ww];
            sh.a.baseArr[t] = base;
        }
        __syncthreads();   // B2

        unsigned pos = sh.a.baseArr[d] + histp[d * 8 + w] + rk;

        if (p < 2) {
            sh.a.skey[pos] = key;
            __syncthreads();   // B3
            key = sh.a.skey[t];
        } else {
            segk[(oct << 9) + pos] = key;
        }
    }

    // Release own run, then wait for the other 7 producers of this (b,v).
    __threadfence();
    __syncthreads();
    if (t == 0) {
        atomicAdd(&done[g], 1);
        while (atomicAdd(&done[g], 0) < 8)
            __builtin_amdgcn_s_sleep(8);
    }
    __syncthreads();
    __threadfence();   // acquire: all 8 runs now visible

    // ---------------- Phase 2: merge + emit ----------------
    #pragma unroll
    for (int j = 0; j < 8; ++j)
        sh.b.runs[(j << 9) + t] = segk[(j << 9) + t];
    __syncthreads();

    u64 k = sh.b.runs[(oct << 9) + t];
    int base7[7], c[7];
    #pragma unroll
    for (int j = 0; j < 7; ++j) {
        base7[j] = (j + (j >= oct ? 1 : 0)) << 9;
        c[j] = 0;
    }
    #pragma unroll
    for (int step = 512; step >= 1; step >>= 1) {
        #pragma unroll
        for (int j = 0; j < 7; ++j) {
            if (c[j] + step <= 512 && sh.b.runs[base7[j] + c[j] + step - 1] < k)
                c[j] += step;
        }
    }
    int rank = t;
    #pragma unroll
    for (int j = 0; j < 7; ++j) rank += c[j];

    {
        int idx = (int)(k & 0xFFFull);
        const float* p = xb + idx * 3;
        sh.b.cxs[t] = p[0]; sh.b.cys[t] = p[1]; sh.b.czs[t] = p[2];
        sh.b.rnk[t] = rank;
    }
    __syncthreads();

    const int tokbase = (b << 13) + (v << 12);
    for (int i = t; i < 512 * F4PT; i += 512) {
        int r = i / F4PT;
        int gg = i - r * F4PT;
        float pxr = sh.b.cxs[r], pyr = sh.b.cys[r], pzr = sh.b.czs[r];
        int d0 = gg << 2;
        float4 w0 = *(const float4*)&sw0[d0];
        float4 w1 = *(const float4*)&sw1[d0];
        float4 w2 = *(const float4*)&sw2[d0];
        float4 cc = *(const float4*)&sc[d0];
        float4 o;
        o.x = pxr*w0.x + pyr*w1.x + pzr*w2.x + cc.x;
        o.y = pxr*w0.y + pyr*w1.y + pzr*w2.y + cc.y;
        o.z = pxr*w0.z + pyr*w1.z + pzr*w2.z + cc.z;
        o.w = pxr*w0.w + pyr*w1.w + pzr*w2.w + cc.w;
        out4[(size_t)(tokbase + sh.b.rnk[r]) * F4PT + gg] = o;
    }
}

extern "C" void kernel_launch(void* const* d_in, const int* in_sizes, int n_in,
                              void* d_out, int out_size, void* d_ws, size_t ws_size,
                              hipStream_t stream) {
    const float* x     = (const float*)d_in[0];
    const float* W     = (const float*)d_in[1];
    const float* bias  = (const float*)d_in[2];
    const float* gamma = (const float*)d_in[3];
    const float* beta  = (const float*)d_in[4];

    u64* kws  = (u64*)d_ws;                 // 32*4096*8 = 1 MB
    int* done = (int*)(kws + 32 * 4096);    // 32 ints

    hipMemsetAsync(done, 0, 32 * sizeof(int), stream);
    hipLaunchKernelGGL(fused_kernel, dim3(BATCH * 16), dim3(512), 0, stream,
                       x, W, bias, gamma, beta, kws, done, (float4*)d_out);
}

// Round 15
// 54.361 us; speedup vs baseline: 2.9200x; 2.9200x over previous
//
#include <hip/hip_runtime.h>
#include <stdint.h>

#define BATCH 16
#define NPTS 4096
#define DIM 384
#define NTOK (2*NPTS)
#define F4PT (DIM/4)   // 96 float4 groups per token
#define NRUN 16        // sorted runs per (b,v)
#define RUN 256        // elements per run

typedef unsigned long long u64;

// Morton spread: place bit b of an 8-bit value at position 3b.
__device__ __forceinline__ uint32_t spread3(uint32_t x) {
    x = (x | (x << 8)) & 0x00F00Fu;
    x = (x | (x << 4)) & 0x0C30C3u;
    x = (x | (x << 2)) & 0x249249u;
    return x;
}

// Exact port of the reference Skilling transform (bits=8, ndim=3).
__device__ __forceinline__ uint32_t hilbert3(uint32_t x0, uint32_t x1, uint32_t x2) {
    #pragma unroll
    for (uint32_t q = 128; q > 1; q >>= 1) {
        uint32_t pm = q - 1;
        if (x0 & q) x0 ^= pm;
        uint32_t t = (x0 ^ x1) & pm;
        if (x1 & q) { x0 ^= pm; } else { x0 ^= t; x1 ^= t; }
        t = (x0 ^ x2) & pm;
        if (x2 & q) { x0 ^= pm; } else { x0 ^= t; x2 ^= t; }
    }
    x1 ^= x0;
    x2 ^= x1;
    uint32_t t = 0;
    #pragma unroll
    for (uint32_t q = 128; q > 1; q >>= 1) { if (x2 & q) t ^= (q - 1); }
    x0 ^= t; x1 ^= t; x2 ^= t;
    return (spread3(x0) << 2) | (spread3(x1) << 1) | spread3(x2);
}

// K1: block = (b, v, sed) with sed in [0,16). 256 threads, 1 element each.
// Batch minmax (48 KB, L2-hot, redundant per block - cheap), code own point,
// 3-pass 8-bit stable radix sort of the 256-element run, write sorted run.
// Key = (code<<12)|global_idx -> all keys distinct.
// 512 blocks -> 2 blocks/CU co-resident: latency of LDS chains/barriers in
// one block is hidden by the other.
__global__ __launch_bounds__(256) void order_radix_s(const float* __restrict__ x,
                                                     u64* __restrict__ kws) {
    const int bi = blockIdx.x;
    const int b = bi >> 5;
    const int v = (bi >> 4) & 1;
    const int sed = bi & 15;
    const int t = threadIdx.x;
    const int lane = t & 63;
    const int w = t >> 6;          // 4 waves

    __shared__ u64 skey[RUN];               // 2 KB
    __shared__ uint32_t hist[3 * 1024];     // per-pass hist[p][d*4+w], 12 KB
    __shared__ uint32_t baseArr[256];       // 1 KB
    __shared__ uint32_t waveTot[4];
    __shared__ float red[4 * 6];

    const float* xb = x + (size_t)b * NPTS * 3;
    const float4* xb4 = (const float4*)xb;

    // --- vectorized batch min/max: 16 points/thread (48 KB, L2-hot) ---
    float mnx = 1e30f, mny = 1e30f, mnz = 1e30f;
    float mxx = -1e30f, mxy = -1e30f, mxz = -1e30f;
    #pragma unroll
    for (int g = 0; g < 4; ++g) {
        float4 q0 = xb4[12*t + 3*g + 0];
        float4 q1 = xb4[12*t + 3*g + 1];
        float4 q2 = xb4[12*t + 3*g + 2];
        float px[4] = {q0.x, q0.w, q1.z, q2.y};
        float py[4] = {q0.y, q1.x, q1.w, q2.z};
        float pz[4] = {q0.z, q1.y, q2.x, q2.w};
        #pragma unroll
        for (int r = 0; r < 4; ++r) {
            mnx = fminf(mnx, px[r]); mxx = fmaxf(mxx, px[r]);
            mny = fminf(mny, py[r]); mxy = fmaxf(mxy, py[r]);
            mnz = fminf(mnz, pz[r]); mxz = fmaxf(mxz, pz[r]);
        }
    }
    #pragma unroll
    for (int off = 32; off > 0; off >>= 1) {
        mnx = fminf(mnx, __shfl_xor(mnx, off));
        mny = fminf(mny, __shfl_xor(mny, off));
        mnz = fminf(mnz, __shfl_xor(mnz, off));
        mxx = fmaxf(mxx, __shfl_xor(mxx, off));
        mxy = fmaxf(mxy, __shfl_xor(mxy, off));
        mxz = fmaxf(mxz, __shfl_xor(mxz, off));
    }
    if (lane == 0) {
        red[w*6+0] = mnx; red[w*6+1] = mny; red[w*6+2] = mnz;
        red[w*6+3] = mxx; red[w*6+4] = mxy; red[w*6+5] = mxz;
    }
    // Zero all per-pass hist regions while the reduction settles.
    #pragma unroll
    for (int c = 0; c < 12; ++c) hist[t + c * 256] = 0u;
    __syncthreads();
    if (t == 0) {
        for (int ww = 1; ww < 4; ++ww) {
            mnx = fminf(mnx, red[ww*6+0]); mny = fminf(mny, red[ww*6+1]);
            mnz = fminf(mnz, red[ww*6+2]); mxx = fmaxf(mxx, red[ww*6+3]);
            mxy = fmaxf(mxy, red[ww*6+4]); mxz = fmaxf(mxz, red[ww*6+5]);
        }
        red[0] = mnx; red[1] = mny; red[2] = mnz;
        red[3] = fmaxf(mxx - mnx, 1e-6f);
        red[4] = fmaxf(mxy - mny, 1e-6f);
        red[5] = fmaxf(mxz - mnz, 1e-6f);
    }
    __syncthreads();
    mnx = red[0]; mny = red[1]; mnz = red[2];
    const float spx = red[3], spy = red[4], spz = red[5];

    // Code own point n0 = sed*256 + t.
    u64 key;
    {
        const int n0 = (sed << 8) + t;
        float cx = xb[3*n0+0], cy = xb[3*n0+1], cz = xb[3*n0+2];
        float gx = fminf(fmaxf(((cx - mnx) / spx) * 255.0f, 0.0f), 255.0f);
        float gy = fminf(fmaxf(((cy - mny) / spy) * 255.0f, 0.0f), 255.0f);
        float gz = fminf(fmaxf(((cz - mnz) / spz) * 255.0f, 0.0f), 255.0f);
        uint32_t ix = (uint32_t)(int)gx;
        uint32_t iy = (uint32_t)(int)gy;
        uint32_t iz = (uint32_t)(int)gz;
        uint32_t a0 = v ? iz : ix;
        uint32_t a2 = v ? ix : iz;
        uint32_t code = hilbert3(a0, iy, a2);
        key = ((u64)code << 12) | (u64)n0;
    }

    const u64 below_mask = (1ull << lane) - 1ull;
    u64* segk = kws + (((b << 1) | v) << 12);

    // 3 stable radix passes, 8-bit digits over key bits [12, 36).
    #pragma unroll
    for (int p = 0; p < 3; ++p) {
        const int sh = 12 + 8 * p;
        uint32_t* histp = hist + p * 1024;

        unsigned d = (unsigned)(key >> sh) & 255u;
        u64 m = ~0ull;
        #pragma unroll
        for (int bit = 0; bit < 8; ++bit) {
            u64 bal = __ballot((int)((d >> bit) & 1u));
            m &= ((d >> bit) & 1u) ? bal : ~bal;
        }
        unsigned rk = (unsigned)__popcll(m & below_mask);
        if (rk == 0u)
            histp[d * 4 + w] = (unsigned)__popcll(m);
        __syncthreads();   // B1

        // All 256 threads: serial-scan own bin's 4 slots; 64-lane shfl scan
        // of bin totals; waveTot combine after barrier.
        unsigned exclw;
        {
            uint32_t* hb = histp + t * 4;
            unsigned running = 0;
            #pragma unroll
            for (int s = 0; s < 4; ++s) {
                unsigned hv = hb[s];
                hb[s] = running;
                running += hv;
            }
            unsigned incl = running;
            #pragma unroll
            for (int off = 1; off < 64; off <<= 1) {
                unsigned nv = __shfl_up(incl, off);
                if (lane >= off) incl += nv;
            }
            if (lane == 63) waveTot[w] = incl;
            exclw = incl - running;
        }
        __syncthreads();   // B1.5

        {
            unsigned base = exclw;
            #pragma unroll
            for (int ww = 0; ww < 4; ++ww)
                if (ww < w) base += waveTot[ww];
            baseArr[t] = base;
        }
        __syncthreads();   // B2

        unsigned pos = baseArr[d] + histp[d * 4 + w] + rk;

        if (p < 2) {
            skey[pos] = key;
            __syncthreads();   // B3
            key = skey[t];
        } else {
            segk[(sed << 8) + pos] = key;
        }
    }
}

// K2: block = (b, v, sed). Loads all 16 sorted runs (32 KB), computes global
// rank of each own-run element (15 interleaved binary searches; keys distinct
// => exact stable argsort), gathers point coords, then directly emits the 256
// output rows: out[b][v*4096 + rank][:] = gamma*(W@p + bias) + beta.
// 512 blocks -> 2 blocks/CU: one block's rank phase overlaps the co-resident
// block's streaming writes.
__global__ __launch_bounds__(256) void merge_emit_kernel(const float* __restrict__ x,
                                                         const float* __restrict__ W,
                                                         const float* __restrict__ bias,
                                                         const float* __restrict__ gamma,
                                                         const float* __restrict__ beta,
                                                         const u64* __restrict__ kws,
                                                         float4* __restrict__ out4) {
    const int bi = blockIdx.x;
    const int b = bi >> 5;
    const int v = (bi >> 4) & 1;
    const int sed = bi & 15;
    const int t = threadIdx.x;

    __shared__ u64 runs[NRUN * RUN];                    // 32 KB
    __shared__ __align__(16) float sw0[DIM], sw1[DIM], sw2[DIM], sc[DIM];  // 6 KB
    __shared__ float cxs[RUN], cys[RUN], czs[RUN];      // 3 KB
    __shared__ int rnk[RUN];                            // 1 KB

    // Coeffs (fused gamma/beta), one v per block.
    if (t < DIM) {
        float g = gamma[v * DIM + t];
        sw0[t] = g * W[t*3+0];
        sw1[t] = g * W[t*3+1];
        sw2[t] = g * W[t*3+2];
        sc[t]  = g * bias[t] + beta[v * DIM + t];
    }
    if (t + 256 < DIM) {
        int i = t + 256;
        float g = gamma[v * DIM + i];
        sw0[i] = g * W[i*3+0];
        sw1[i] = g * W[i*3+1];
        sw2[i] = g * W[i*3+2];
        sc[i]  = g * bias[i] + beta[v * DIM + i];
    }

    // Load the 16 sorted runs for this (b, v).
    const u64* segk = kws + (((b << 1) | v) << 12);
    #pragma unroll
    for (int j = 0; j < NRUN; ++j)
        runs[(j << 8) + t] = segk[(j << 8) + t];
    __syncthreads();

    // Rank = own position + count-less in the other 15 runs.
    u64 k = runs[(sed << 8) + t];
    int base15[15], c[15];
    #pragma unroll
    for (int j = 0; j < 15; ++j) {
        base15[j] = (j + (j >= sed ? 1 : 0)) << 8;
        c[j] = 0;
    }
    // Step-outer: the 15 dependent LDS chains interleave.
    #pragma unroll
    for (int step = RUN; step >= 1; step >>= 1) {
        #pragma unroll
        for (int j = 0; j < 15; ++j) {
            if (c[j] + step <= RUN && runs[base15[j] + c[j] + step - 1] < k)
                c[j] += step;
        }
    }
    int rank = t;
    #pragma unroll
    for (int j = 0; j < 15; ++j) rank += c[j];

    // Gather own point's coords.
    {
        int idx = (int)(k & 0xFFFull);
        const float* p = x + (size_t)b * NPTS * 3 + idx * 3;
        cxs[t] = p[0]; cys[t] = p[1]; czs[t] = p[2];
        rnk[t] = rank;
    }
    __syncthreads();

    // Emit 256 rows x 96 float4 groups; lane-contiguous within rows.
    const int tokbase = (b << 13) + (v << 12);
    for (int i = t; i < RUN * F4PT; i += 256) {
        int r = i / F4PT;
        int g = i - r * F4PT;
        float pxr = cxs[r], pyr = cys[r], pzr = czs[r];
        int d0 = g << 2;
        float4 w0 = *(const float4*)&sw0[d0];
        float4 w1 = *(const float4*)&sw1[d0];
        float4 w2 = *(const float4*)&sw2[d0];
        float4 cc = *(const float4*)&sc[d0];
        float4 o;
        o.x = pxr*w0.x + pyr*w1.x + pzr*w2.x + cc.x;
        o.y = pxr*w0.y + pyr*w1.y + pzr*w2.y + cc.y;
        o.z = pxr*w0.z + pyr*w1.z + pzr*w2.z + cc.z;
        o.w = pxr*w0.w + pyr*w1.w + pzr*w2.w + cc.w;
        out4[(size_t)(tokbase + rnk[r]) * F4PT + g] = o;
    }
}

extern "C" void kernel_launch(void* const* d_in, const int* in_sizes, int n_in,
                              void* d_out, int out_size, void* d_ws, size_t ws_size,
                              hipStream_t stream) {
    const float* x     = (const float*)d_in[0];
    const float* W     = (const float*)d_in[1];
    const float* bias  = (const float*)d_in[2];
    const float* gamma = (const float*)d_in[3];
    const float* beta  = (const float*)d_in[4];

    u64* kws = (u64*)d_ws;   // 32*4096*8 = 1 MB

    hipLaunchKernelGGL(order_radix_s,     dim3(BATCH * 32), dim3(256), 0, stream, x, kws);
    hipLaunchKernelGGL(merge_emit_kernel, dim3(BATCH * 32), dim3(256), 0, stream,
                       x, W, bias, gamma, beta, kws, (float4*)d_out);
}

// Round 16
// 49.595 us; speedup vs baseline: 3.2006x; 1.0961x over previous
//
#include <hip/hip_runtime.h>
#include <stdint.h>

#define BATCH 16
#define NPTS 4096
#define DIM 384
#define NTOK (2*NPTS)
#define F4PT (DIM/4)   // 96 float4 groups per token

typedef unsigned long long u64;

// Morton spread: place bit b of an 8-bit value at position 3b.
__device__ __forceinline__ uint32_t spread3(uint32_t x) {
    x = (x | (x << 8)) & 0x00F00Fu;
    x = (x | (x << 4)) & 0x0C30C3u;
    x = (x | (x << 2)) & 0x249249u;
    return x;
}

// Exact port of the reference Skilling transform (bits=8, ndim=3).
__device__ __forceinline__ uint32_t hilbert3(uint32_t x0, uint32_t x1, uint32_t x2) {
    #pragma unroll
    for (uint32_t q = 128; q > 1; q >>= 1) {
        uint32_t pm = q - 1;
        if (x0 & q) x0 ^= pm;
        uint32_t t = (x0 ^ x1) & pm;
        if (x1 & q) { x0 ^= pm; } else { x0 ^= t; x1 ^= t; }
        t = (x0 ^ x2) & pm;
        if (x2 & q) { x0 ^= pm; } else { x0 ^= t; x2 ^= t; }
    }
    x1 ^= x0;
    x2 ^= x1;
    uint32_t t = 0;
    #pragma unroll
    for (uint32_t q = 128; q > 1; q >>= 1) { if (x2 & q) t ^= (q - 1); }
    x0 ^= t; x1 ^= t; x2 ^= t;
    return (spread3(x0) << 2) | (spread3(x1) << 1) | spread3(x2);
}

// K1: block = (b, v, octant). 512 threads, 1 element each. Batch minmax
// (48 KB, L2-hot, redundant per block - cheap), code own point, 3-pass 8-bit
// STABLE radix sort of the 512-element octant by code only (stability makes
// idx a pure payload), write sorted run as split u32 code / u16 idx arrays.
__global__ __launch_bounds__(512) void order_radix_o(const float* __restrict__ x,
                                                     uint32_t* __restrict__ segc_all,
                                                     unsigned short* __restrict__ segi_all) {
    const int bi = blockIdx.x;
    const int b = bi >> 4;
    const int v = (bi >> 3) & 1;
    const int oct = bi & 7;
    const int t = threadIdx.x;
    const int lane = t & 63;
    const int w = t >> 6;          // 8 waves

    __shared__ uint32_t scode[512];          // 2 KB
    __shared__ unsigned short slocal[512];   // 1 KB
    __shared__ uint32_t hist[3 * 2048];      // per-pass hist[p][d*8+w], 24 KB
    __shared__ uint32_t baseArr[256];        // 1 KB
    __shared__ uint32_t waveTot[4];
    __shared__ float red[8 * 6];

    const float* xb = x + (size_t)b * NPTS * 3;
    const float4* xb4 = (const float4*)xb;

    // --- vectorized batch min/max: 8 points/thread ---
    float mnx = 1e30f, mny = 1e30f, mnz = 1e30f;
    float mxx = -1e30f, mxy = -1e30f, mxz = -1e30f;
    #pragma unroll
    for (int h = 0; h < 2; ++h) {
        float4 q0 = xb4[h * 1536 + 3 * t + 0];
        float4 q1 = xb4[h * 1536 + 3 * t + 1];
        float4 q2 = xb4[h * 1536 + 3 * t + 2];
        float px[4] = {q0.x, q0.w, q1.z, q2.y};
        float py[4] = {q0.y, q1.x, q1.w, q2.z};
        float pz[4] = {q0.z, q1.y, q2.x, q2.w};
        #pragma unroll
        for (int r = 0; r < 4; ++r) {
            mnx = fminf(mnx, px[r]); mxx = fmaxf(mxx, px[r]);
            mny = fminf(mny, py[r]); mxy = fmaxf(mxy, py[r]);
            mnz = fminf(mnz, pz[r]); mxz = fmaxf(mxz, pz[r]);
        }
    }
    #pragma unroll
    for (int off = 32; off > 0; off >>= 1) {
        mnx = fminf(mnx, __shfl_xor(mnx, off));
        mny = fminf(mny, __shfl_xor(mny, off));
        mnz = fminf(mnz, __shfl_xor(mnz, off));
        mxx = fmaxf(mxx, __shfl_xor(mxx, off));
        mxy = fmaxf(mxy, __shfl_xor(mxy, off));
        mxz = fmaxf(mxz, __shfl_xor(mxz, off));
    }
    if (lane == 0) {
        red[w*6+0] = mnx; red[w*6+1] = mny; red[w*6+2] = mnz;
        red[w*6+3] = mxx; red[w*6+4] = mxy; red[w*6+5] = mxz;
    }
    // Zero all per-pass hist regions while the reduction settles.
    #pragma unroll
    for (int c = 0; c < 12; ++c) hist[t + c * 512] = 0u;
    __syncthreads();
    if (t == 0) {
        for (int ww = 1; ww < 8; ++ww) {
            mnx = fminf(mnx, red[ww*6+0]); mny = fminf(mny, red[ww*6+1]);
            mnz = fminf(mnz, red[ww*6+2]); mxx = fmaxf(mxx, red[ww*6+3]);
            mxy = fmaxf(mxy, red[ww*6+4]); mxz = fmaxf(mxz, red[ww*6+5]);
        }
        red[0] = mnx; red[1] = mny; red[2] = mnz;
        red[3] = fmaxf(mxx - mnx, 1e-6f);
        red[4] = fmaxf(mxy - mny, 1e-6f);
        red[5] = fmaxf(mxz - mnz, 1e-6f);
    }
    __syncthreads();
    mnx = red[0]; mny = red[1]; mnz = red[2];
    const float spx = red[3], spy = red[4], spz = red[5];

    // Code own point n0 = oct*512 + t.
    uint32_t code;
    unsigned short myidx;
    {
        const int n0 = (oct << 9) + t;
        float cx = xb[3*n0+0], cy = xb[3*n0+1], cz = xb[3*n0+2];
        float gx = fminf(fmaxf(((cx - mnx) / spx) * 255.0f, 0.0f), 255.0f);
        float gy = fminf(fmaxf(((cy - mny) / spy) * 255.0f, 0.0f), 255.0f);
        float gz = fminf(fmaxf(((cz - mnz) / spz) * 255.0f, 0.0f), 255.0f);
        uint32_t ix = (uint32_t)(int)gx;
        uint32_t iy = (uint32_t)(int)gy;
        uint32_t iz = (uint32_t)(int)gz;
        uint32_t a0 = v ? iz : ix;
        uint32_t a2 = v ? ix : iz;
        code = hilbert3(a0, iy, a2);
        myidx = (unsigned short)n0;
    }

    const u64 below_mask = (1ull << lane) - 1ull;
    uint32_t* segc = segc_all + (((b << 1) | v) << 12);
    unsigned short* segi = segi_all + (((b << 1) | v) << 12);

    // 3 stable radix passes, 8-bit digits over code bits [0, 24).
    #pragma unroll
    for (int p = 0; p < 3; ++p) {
        const int sh = 8 * p;
        uint32_t* histp = hist + p * 2048;

        unsigned d = (code >> sh) & 255u;
        u64 m = ~0ull;
        #pragma unroll
        for (int bit = 0; bit < 8; ++bit) {
            u64 bal = __ballot((int)((d >> bit) & 1u));
            m &= ((d >> bit) & 1u) ? bal : ~bal;
        }
        unsigned rk = (unsigned)__popcll(m & below_mask);
        if (rk == 0u)
            histp[d * 8 + w] = (unsigned)__popcll(m);
        __syncthreads();   // B1

        // 256 threads: serial-scan own bin's 8 slots; 4-wave shfl scan of
        // bin totals; waveTot combine after barrier.
        unsigned exclw = 0;
        if (t < 256) {
            uint32_t* hb = histp + t * 8;
            unsigned running = 0;
            #pragma unroll
            for (int s = 0; s < 8; ++s) {
                unsigned hv = hb[s];
                hb[s] = running;
                running += hv;
            }
            unsigned incl = running;
            #pragma unroll
            for (int off = 1; off < 64; off <<= 1) {
                unsigned nv = __shfl_up(incl, off);
                if (lane >= off) incl += nv;
            }
            if (lane == 63) waveTot[w] = incl;
            exclw = incl - running;
        }
        __syncthreads();   // B1.5

        if (t < 256) {
            unsigned base = exclw;
            #pragma unroll
            for (int ww = 0; ww < 4; ++ww)
                if (ww < w) base += waveTot[ww];
            baseArr[t] = base;
        }
        __syncthreads();   // B2

        unsigned pos = baseArr[d] + histp[d * 8 + w] + rk;

        if (p < 2) {
            scode[pos] = code;
            slocal[pos] = myidx;
            __syncthreads();   // B3
            code = scode[t];
            myidx = slocal[t];
        } else {
            segc[(oct << 9) + pos] = code;
            segi[(oct << 9) + pos] = myidx;
        }
    }
}

// K2: block = (b, v, octant). Early-loads own code/idx/coords (hidden under
// staging), stages all 8 runs' CODES (16 KB, uint4 loads), ranks each own
// element via 7 interleaved binary searches with run-order tie-break
// (count in run j = #{c' < c + (j<sed)} -- exact argsort rank since gidx
// ranges of runs are disjoint and ordered), then emits the 512 output rows.
__global__ __launch_bounds__(512) void merge_emit_kernel(const float* __restrict__ x,
                                                         const float* __restrict__ W,
                                                         const float* __restrict__ bias,
                                                         const float* __restrict__ gamma,
                                                         const float* __restrict__ beta,
                                                         const uint32_t* __restrict__ segc_all,
                                                         const unsigned short* __restrict__ segi_all,
                                                         float4* __restrict__ out4) {
    const int bi = blockIdx.x;
    const int b = bi >> 4;
    const int v = (bi >> 3) & 1;
    const int oct = bi & 7;
    const int t = threadIdx.x;

    __shared__ uint32_t runs[8 * 512];                  // 16 KB
    __shared__ __align__(16) float sw0[DIM], sw1[DIM], sw2[DIM], sc[DIM];  // 6 KB
    __shared__ float cxs[512], cys[512], czs[512];      // 6 KB
    __shared__ int rnk[512];                            // 2 KB

    const uint32_t* segc = segc_all + (((b << 1) | v) << 12);
    const unsigned short* segi = segi_all + (((b << 1) | v) << 12);

    // Early independent loads: own code, idx, coords (chained; lands under
    // the staging + barrier below).
    uint32_t kc = segc[(oct << 9) + t];
    int idx = (int)segi[(oct << 9) + t];
    const float* p = x + (size_t)b * NPTS * 3 + idx * 3;
    float pcx = p[0], pcy = p[1], pcz = p[2];

    // Coeffs (fused gamma/beta), one v per block.
    if (t < DIM) {
        float g = gamma[v * DIM + t];
        sw0[t] = g * W[t*3+0];
        sw1[t] = g * W[t*3+1];
        sw2[t] = g * W[t*3+2];
        sc[t]  = g * bias[t] + beta[v * DIM + t];
    }

    // Stage all 8 runs' codes as uint4 (2 x 16 B per thread).
    {
        const uint4* s4 = (const uint4*)segc;
        uint4* r4 = (uint4*)runs;
        r4[t] = s4[t];
        r4[t + 512] = s4[t + 512];
    }
    __syncthreads();

    // Rank = own position + counts in the other 7 runs.
    int rank = t;
    {
        int base7[7];
        uint32_t thr7[7];
        int c[7];
        #pragma unroll
        for (int j = 0; j < 7; ++j) {
            int oq = j + (j >= oct ? 1 : 0);
            base7[j] = oq << 9;
            thr7[j] = kc + (oq < oct ? 1u : 0u);
            c[j] = 0;
        }
        #pragma unroll
        for (int step = 512; step >= 1; step >>= 1) {
            #pragma unroll
            for (int j = 0; j < 7; ++j) {
                if (c[j] + step <= 512 && runs[base7[j] + c[j] + step - 1] < thr7[j])
                    c[j] += step;
            }
        }
        #pragma unroll
        for (int j = 0; j < 7; ++j) rank += c[j];
    }

    cxs[t] = pcx; cys[t] = pcy; czs[t] = pcz;
    rnk[t] = rank;
    __syncthreads();

    // Emit 512 rows x 96 float4 groups; lane-contiguous within rows.
    const int tokbase = (b << 13) + (v << 12);
    for (int i = t; i < 512 * F4PT; i += 512) {
        int r = i / F4PT;
        int g = i - r * F4PT;
        float pxr = cxs[r], pyr = cys[r], pzr = czs[r];
        int d0 = g << 2;
        float4 w0 = *(const float4*)&sw0[d0];
        float4 w1 = *(const float4*)&sw1[d0];
        float4 w2 = *(const float4*)&sw2[d0];
        float4 cc = *(const float4*)&sc[d0];
        float4 o;
        o.x = pxr*w0.x + pyr*w1.x + pzr*w2.x + cc.x;
        o.y = pxr*w0.y + pyr*w1.y + pzr*w2.y + cc.y;
        o.z = pxr*w0.z + pyr*w1.z + pzr*w2.z + cc.z;
        o.w = pxr*w0.w + pyr*w1.w + pzr*w2.w + cc.w;
        out4[(size_t)(tokbase + rnk[r]) * F4PT + g] = o;
    }
}

extern "C" void kernel_launch(void* const* d_in, const int* in_sizes, int n_in,
                              void* d_out, int out_size, void* d_ws, size_t ws_size,
                              hipStream_t stream) {
    const float* x     = (const float*)d_in[0];
    const float* W     = (const float*)d_in[1];
    const float* bias  = (const float*)d_in[2];
    const float* gamma = (const float*)d_in[3];
    const float* beta  = (const float*)d_in[4];

    uint32_t* segc_all = (uint32_t*)d_ws;                       // 32*4096*4 = 512 KB
    unsigned short* segi_all = (unsigned short*)(segc_all + 32 * 4096);  // 256 KB

    hipLaunchKernelGGL(order_radix_o,     dim3(BATCH * 16), dim3(512), 0, stream,
                       x, segc_all, segi_all);
    hipLaunchKernelGGL(merge_emit_kernel, dim3(BATCH * 16), dim3(512), 0, stream,
                       x, W, bias, gamma, beta, segc_all, segi_all, (float4*)d_out);
}